// Round 6
// baseline (47.702 us; speedup 1.0000x reference)
//
#include <hip/hip_runtime.h>
#include <math.h>

#define N_STATIONS 276
#define CTX4 96            // float4s per z row
#define TGT 96
#define BATCH 4096

#define SLOTS_MAX (BATCH + 3 * N_STATIONS)   // quad-padded list slots: 4924
#define NWG 1232                              // >= ceil(SLOTS_MAX/4)=1231, multiple of 8
#define CPX (NWG / 8)                         // 154 blocks per XCD chunk

// ---------- kernel 1: per-station lists, padded to multiple of 4 ----------
// ws layout: ws[0] = nquads; ws[1..1+SLOTS_MAX) = order (sample ids, -1 = pad)
__global__ __launch_bounds__(1024) void build_quads(
    const int* __restrict__ stations,
    int* __restrict__ ws)
{
    __shared__ int cnt[N_STATIONS];
    __shared__ int cnt2[N_STATIONS];
    __shared__ int poff[N_STATIONS + 1];
    const int tid = threadIdx.x;
    for (int i = tid; i < N_STATIONS; i += 1024) { cnt[i] = 0; cnt2[i] = 0; }
    __syncthreads();
    for (int b = tid; b < BATCH; b += 1024) atomicAdd(&cnt[stations[b]], 1);
    __syncthreads();
    // wave-parallel inclusive scan of quad-ceil(cnt) over 5 chunks of 64
    if (tid < 64) {
        int run = 0;
        for (int base = 0; base < N_STATIONS; base += 64) {
            const int i = base + tid;
            int v = (i < N_STATIONS) ? ((cnt[i] + 3) & ~3) : 0;
#pragma unroll
            for (int off = 1; off < 64; off <<= 1) {
                int u = __shfl_up(v, off, 64);
                if (tid >= off) v += u;
            }
            if (i < N_STATIONS) poff[i + 1] = run + v;
            run += __shfl(v, 63, 64);
        }
        if (tid == 0) poff[0] = 0;
    }
    __syncthreads();
    int* order = ws + 1;
    for (int b = tid; b < BATCH; b += 1024) {
        int s = stations[b];
        int p = atomicAdd(&cnt2[s], 1);
        order[poff[s] + p] = b;          // within-station order irrelevant to output values
    }
    for (int s = tid; s < N_STATIONS; s += 1024) {
        int c = cnt[s], e = (c + 3) & ~3;
        for (int j = c; j < e; ++j) order[poff[s] + j] = -1;  // disjoint slots, no sync needed
    }
    if (tid == 0) ws[0] = poff[N_STATIONS] / 4;
}

// ---------- kernel 2: one block per same-station sample QUAD ----------
// 256 thr = 16 groups x 16 lanes; group g computes rows g*6..g*6+5 for 4 samples.
// W rows streamed through registers (L2-served via XCD swizzle); z in registers.
__global__ __launch_bounds__(256) void nlinear_quads(
    const float* __restrict__ z,        // (BATCH, CTX)
    const int*   __restrict__ stations,
    const float* __restrict__ W,        // (N_STATIONS, TGT, CTX)
    const float* __restrict__ bias,     // (N_STATIONS, TGT)
    const float* __restrict__ loc,
    const float* __restrict__ scale,
    const int*   __restrict__ ws,
    float*       __restrict__ out)      // (BATCH, TGT)
{
    // XCD swizzle: consecutive qids (same station) land on the same XCD's L2
    const int bid = blockIdx.x;
    const int qid = (bid & 7) * CPX + (bid >> 3);
    const int nquads = ws[0];
    if (qid >= nquads) return;

    const int* order = ws + 1;
    const int i0 = order[qid * 4];
    int i1 = order[qid * 4 + 1];
    int i2 = order[qid * 4 + 2];
    int i3 = order[qid * 4 + 3];
    const bool v1 = (i1 >= 0), v2 = (i2 >= 0), v3 = (i3 >= 0);
    if (!v1) i1 = i0;
    if (!v2) i2 = i0;
    if (!v3) i3 = i0;

    const int s = stations[i0];
    const float lc = loc[s], sc = scale[s], inv = 1.0f / sc;

    const int tid = threadIdx.x;
    const int t   = tid & 15;
    const int grp = tid >> 4;

    // normalized z rows -> registers (lane t owns float4s {t, t+16, ..., t+80})
    const float4* z4 = reinterpret_cast<const float4*>(z);
    float4 z0[6], z1[6], z2[6], z3[6];
#pragma unroll
    for (int k = 0; k < 6; ++k) {
        float4 a = z4[(size_t)i0 * CTX4 + t + 16 * k];
        float4 b = z4[(size_t)i1 * CTX4 + t + 16 * k];
        float4 c = z4[(size_t)i2 * CTX4 + t + 16 * k];
        float4 d = z4[(size_t)i3 * CTX4 + t + 16 * k];
        z0[k].x = (a.x - lc) * inv; z0[k].y = (a.y - lc) * inv;
        z0[k].z = (a.z - lc) * inv; z0[k].w = (a.w - lc) * inv;
        z1[k].x = (b.x - lc) * inv; z1[k].y = (b.y - lc) * inv;
        z1[k].z = (b.z - lc) * inv; z1[k].w = (b.w - lc) * inv;
        z2[k].x = (c.x - lc) * inv; z2[k].y = (c.y - lc) * inv;
        z2[k].z = (c.z - lc) * inv; z2[k].w = (c.w - lc) * inv;
        z3[k].x = (d.x - lc) * inv; z3[k].y = (d.y - lc) * inv;
        z3[k].z = (d.z - lc) * inv; z3[k].w = (d.w - lc) * inv;
    }

    const float4* w4 = reinterpret_cast<const float4*>(W) + (size_t)s * TGT * CTX4;

#pragma unroll
    for (int r = 0; r < 6; ++r) {
        const int row = grp * 6 + r;
        const float4* wr = w4 + (size_t)row * CTX4;
        float4 a0 = {0,0,0,0}, a1 = {0,0,0,0}, a2 = {0,0,0,0}, a3 = {0,0,0,0};
#pragma unroll
        for (int k = 0; k < 6; ++k) {
            float4 w = wr[t + 16 * k];
            a0.x += w.x * z0[k].x; a0.y += w.y * z0[k].y;
            a0.z += w.z * z0[k].z; a0.w += w.w * z0[k].w;
            a1.x += w.x * z1[k].x; a1.y += w.y * z1[k].y;
            a1.z += w.z * z1[k].z; a1.w += w.w * z1[k].w;
            a2.x += w.x * z2[k].x; a2.y += w.y * z2[k].y;
            a2.z += w.z * z2[k].z; a2.w += w.w * z2[k].w;
            a3.x += w.x * z3[k].x; a3.y += w.y * z3[k].y;
            a3.z += w.z * z3[k].z; a3.w += w.w * z3[k].w;
        }
        float s0 = (a0.x + a0.y) + (a0.z + a0.w);
        float s1 = (a1.x + a1.y) + (a1.z + a1.w);
        float s2 = (a2.x + a2.y) + (a2.z + a2.w);
        float s3 = (a3.x + a3.y) + (a3.z + a3.w);
#pragma unroll
        for (int off = 8; off > 0; off >>= 1) {
            s0 += __shfl_xor(s0, off, 64);
            s1 += __shfl_xor(s1, off, 64);
            s2 += __shfl_xor(s2, off, 64);
            s3 += __shfl_xor(s3, off, 64);
        }
        // lanes 0..3 write samples 0..3 (guarded for pads)
        const bool wv = (t == 0) || (t == 1 && v1) || (t == 2 && v2) || (t == 3 && v3);
        if (wv) {
            const int   id = (t == 0) ? i0 : (t == 1) ? i1 : (t == 2) ? i2 : i3;
            const float sv = (t == 0) ? s0 : (t == 1) ? s1 : (t == 2) ? s2 : s3;
            float v = (sv + bias[(size_t)s * TGT + row]) * sc + lc;
            out[(size_t)id * TGT + row] = fmaxf(v, 0.f) + log1pf(expf(-fabsf(v)));
        }
    }
}

extern "C" void kernel_launch(void* const* d_in, const int* in_sizes, int n_in,
                              void* d_out, int out_size, void* d_ws, size_t ws_size,
                              hipStream_t stream) {
    const float* z        = (const float*)d_in[0];
    const int*   stations = (const int*)  d_in[1];
    const float* W        = (const float*)d_in[2];
    const float* bias     = (const float*)d_in[3];
    const float* loc      = (const float*)d_in[4];
    const float* scale    = (const float*)d_in[5];
    float* out = (float*)d_out;
    int* ws = (int*)d_ws;

    build_quads<<<1, 1024, 0, stream>>>(stations, ws);
    nlinear_quads<<<NWG, 256, 0, stream>>>(z, stations, W, bias, loc, scale, ws, out);
}

// Round 7
// 34.711 us; speedup vs baseline: 1.3743x; 1.3743x over previous
//
#include <hip/hip_runtime.h>
#include <math.h>

#define N_STATIONS 276
#define CTX4 96            // float4s per z row
#define TGT 96
#define BATCH 4096

#define SLOTS_MAX (BATCH + 3 * N_STATIONS)   // quad-padded list slots: 4924
#define NWG 1232                              // >= ceil(SLOTS_MAX/4)=1231, multiple of 8
#define CPX (NWG / 8)                         // 154 blocks per XCD chunk

// ---------- kernel 1: per-station lists, padded to multiple of 4 ----------
// ws layout: ws[0] = nquads; ws[1..1+SLOTS_MAX) = order (sample ids, -1 = pad)
__global__ __launch_bounds__(1024) void build_quads(
    const int* __restrict__ stations,
    int* __restrict__ ws)
{
    __shared__ int cnt[N_STATIONS];
    __shared__ int cnt2[N_STATIONS];
    __shared__ int poff[N_STATIONS + 1];
    const int tid = threadIdx.x;
    for (int i = tid; i < N_STATIONS; i += 1024) { cnt[i] = 0; cnt2[i] = 0; }
    __syncthreads();
    for (int b = tid; b < BATCH; b += 1024) atomicAdd(&cnt[stations[b]], 1);
    __syncthreads();
    // wave-parallel inclusive scan of quad-ceil(cnt) over 5 chunks of 64
    if (tid < 64) {
        int run = 0;
        for (int base = 0; base < N_STATIONS; base += 64) {
            const int i = base + tid;
            int v = (i < N_STATIONS) ? ((cnt[i] + 3) & ~3) : 0;
#pragma unroll
            for (int off = 1; off < 64; off <<= 1) {
                int u = __shfl_up(v, off, 64);
                if (tid >= off) v += u;
            }
            if (i < N_STATIONS) poff[i + 1] = run + v;
            run += __shfl(v, 63, 64);
        }
        if (tid == 0) poff[0] = 0;
    }
    __syncthreads();
    int* order = ws + 1;
    for (int b = tid; b < BATCH; b += 1024) {
        int s = stations[b];
        int p = atomicAdd(&cnt2[s], 1);
        order[poff[s] + p] = b;          // within-station order irrelevant to output values
    }
    for (int s = tid; s < N_STATIONS; s += 1024) {
        int c = cnt[s], e = (c + 3) & ~3;
        for (int j = c; j < e; ++j) order[poff[s] + j] = -1;  // disjoint slots, no sync needed
    }
    if (tid == 0) ws[0] = poff[N_STATIONS] / 4;
}

// ---------- kernel 2: one block per same-station sample QUAD ----------
// 256 thr = 8 groups x 32 lanes; group g computes rows g*12..g*12+11 for 4 samples.
// z: 12 floats/sample/lane (48 VGPR), laundered so the compiler can't remat.
// W rows streamed, 32 lanes x 16B = 512B coalesced segments, L2-served via XCD swizzle.
__global__ __launch_bounds__(256, 4) void nlinear_quads(
    const float* __restrict__ z,        // (BATCH, CTX)
    const int*   __restrict__ stations,
    const float* __restrict__ W,        // (N_STATIONS, TGT, CTX)
    const float* __restrict__ bias,     // (N_STATIONS, TGT)
    const float* __restrict__ loc,
    const float* __restrict__ scale,
    const int*   __restrict__ ws,
    float*       __restrict__ out)      // (BATCH, TGT)
{
    // XCD swizzle: consecutive qids (same station) land on the same XCD's L2
    const int bid = blockIdx.x;
    const int qid = (bid & 7) * CPX + (bid >> 3);
    const int nquads = ws[0];
    if (qid >= nquads) return;

    const int* order = ws + 1;
    const int i0 = order[qid * 4];
    int i1 = order[qid * 4 + 1];
    int i2 = order[qid * 4 + 2];
    int i3 = order[qid * 4 + 3];
    const bool v1 = (i1 >= 0), v2 = (i2 >= 0), v3 = (i3 >= 0);
    if (!v1) i1 = i0;
    if (!v2) i2 = i0;
    if (!v3) i3 = i0;

    const int s = stations[i0];
    const float lc = loc[s], sc = scale[s], inv = 1.0f / sc;

    const int tid = threadIdx.x;
    const int t   = tid & 31;   // lane in 32-lane group
    const int grp = tid >> 5;   // group 0..7

    // normalized z -> registers: lane t owns float4s {t, t+32, t+64} of each sample
    const float4* z4 = reinterpret_cast<const float4*>(z);
    float4 z0[3], z1[3], z2[3], z3[3];
#pragma unroll
    for (int k = 0; k < 3; ++k) {
        float4 a = z4[(size_t)i0 * CTX4 + t + 32 * k];
        float4 b = z4[(size_t)i1 * CTX4 + t + 32 * k];
        float4 c = z4[(size_t)i2 * CTX4 + t + 32 * k];
        float4 d = z4[(size_t)i3 * CTX4 + t + 32 * k];
        z0[k].x = (a.x - lc) * inv; z0[k].y = (a.y - lc) * inv;
        z0[k].z = (a.z - lc) * inv; z0[k].w = (a.w - lc) * inv;
        z1[k].x = (b.x - lc) * inv; z1[k].y = (b.y - lc) * inv;
        z1[k].z = (b.z - lc) * inv; z1[k].w = (b.w - lc) * inv;
        z2[k].x = (c.x - lc) * inv; z2[k].y = (c.y - lc) * inv;
        z2[k].z = (c.z - lc) * inv; z2[k].w = (c.w - lc) * inv;
        z3[k].x = (d.x - lc) * inv; z3[k].y = (d.y - lc) * inv;
        z3[k].z = (d.z - lc) * inv; z3[k].w = (d.w - lc) * inv;
    }
    // launder: make z registers opaque so the compiler can't re-load/recompute them
#pragma unroll
    for (int k = 0; k < 3; ++k) {
        asm volatile("" : "+v"(z0[k].x), "+v"(z0[k].y), "+v"(z0[k].z), "+v"(z0[k].w));
        asm volatile("" : "+v"(z1[k].x), "+v"(z1[k].y), "+v"(z1[k].z), "+v"(z1[k].w));
        asm volatile("" : "+v"(z2[k].x), "+v"(z2[k].y), "+v"(z2[k].z), "+v"(z2[k].w));
        asm volatile("" : "+v"(z3[k].x), "+v"(z3[k].y), "+v"(z3[k].z), "+v"(z3[k].w));
    }

    const float4* w4 = reinterpret_cast<const float4*>(W) + (size_t)s * TGT * CTX4;

    for (int r = 0; r < 12; ++r) {
        const int row = grp * 12 + r;
        const float4* wr = w4 + (size_t)row * CTX4;
        const float4 w0 = wr[t];
        const float4 w1 = wr[t + 32];
        const float4 w2 = wr[t + 64];
        float s0 = w0.x * z0[0].x + w0.y * z0[0].y + w0.z * z0[0].z + w0.w * z0[0].w
                 + w1.x * z0[1].x + w1.y * z0[1].y + w1.z * z0[1].z + w1.w * z0[1].w
                 + w2.x * z0[2].x + w2.y * z0[2].y + w2.z * z0[2].z + w2.w * z0[2].w;
        float s1 = w0.x * z1[0].x + w0.y * z1[0].y + w0.z * z1[0].z + w0.w * z1[0].w
                 + w1.x * z1[1].x + w1.y * z1[1].y + w1.z * z1[1].z + w1.w * z1[1].w
                 + w2.x * z1[2].x + w2.y * z1[2].y + w2.z * z1[2].z + w2.w * z1[2].w;
        float s2 = w0.x * z2[0].x + w0.y * z2[0].y + w0.z * z2[0].z + w0.w * z2[0].w
                 + w1.x * z2[1].x + w1.y * z2[1].y + w1.z * z2[1].z + w1.w * z2[1].w
                 + w2.x * z2[2].x + w2.y * z2[2].y + w2.z * z2[2].z + w2.w * z2[2].w;
        float s3 = w0.x * z3[0].x + w0.y * z3[0].y + w0.z * z3[0].z + w0.w * z3[0].w
                 + w1.x * z3[1].x + w1.y * z3[1].y + w1.z * z3[1].z + w1.w * z3[1].w
                 + w2.x * z3[2].x + w2.y * z3[2].y + w2.z * z3[2].z + w2.w * z3[2].w;
#pragma unroll
        for (int off = 16; off > 0; off >>= 1) {
            s0 += __shfl_xor(s0, off, 64);
            s1 += __shfl_xor(s1, off, 64);
            s2 += __shfl_xor(s2, off, 64);
            s3 += __shfl_xor(s3, off, 64);
        }
        // lanes 0..3 of each group write samples 0..3 (guarded for pads)
        const bool wv = (t == 0) || (t == 1 && v1) || (t == 2 && v2) || (t == 3 && v3);
        if (wv) {
            const int   id = (t == 0) ? i0 : (t == 1) ? i1 : (t == 2) ? i2 : i3;
            const float sv = (t == 0) ? s0 : (t == 1) ? s1 : (t == 2) ? s2 : s3;
            float v = (sv + bias[(size_t)s * TGT + row]) * sc + lc;
            out[(size_t)id * TGT + row] = fmaxf(v, 0.f) + log1pf(expf(-fabsf(v)));
        }
    }
}

extern "C" void kernel_launch(void* const* d_in, const int* in_sizes, int n_in,
                              void* d_out, int out_size, void* d_ws, size_t ws_size,
                              hipStream_t stream) {
    const float* z        = (const float*)d_in[0];
    const int*   stations = (const int*)  d_in[1];
    const float* W        = (const float*)d_in[2];
    const float* bias     = (const float*)d_in[3];
    const float* loc      = (const float*)d_in[4];
    const float* scale    = (const float*)d_in[5];
    float* out = (float*)d_out;
    int* ws = (int*)d_ws;

    build_quads<<<1, 1024, 0, stream>>>(stations, ws);
    nlinear_quads<<<NWG, 256, 0, stream>>>(z, stations, W, bias, loc, scale, ws, out);
}

// Round 8
// 32.150 us; speedup vs baseline: 1.4837x; 1.0797x over previous
//
#include <hip/hip_runtime.h>
#include <math.h>

#define N_STATIONS 276
#define CTX4 96            // float4s per z row
#define TGT 96
#define BATCH 4096

#define SLOTS_MAX (BATCH + 3 * N_STATIONS)   // quad-padded list slots: 4924
#define NWG 1232                              // >= ceil(SLOTS_MAX/4)=1231, multiple of 8
#define CPX (NWG / 8)                         // 154 blocks per XCD chunk

// ---------- kernel 1: per-station lists, padded to multiple of 4 ----------
// ws layout: ws[0] = nquads; ws[1..1+SLOTS_MAX) = order (sample ids, -1 = pad)
__global__ __launch_bounds__(1024) void build_quads(
    const int* __restrict__ stations,
    int* __restrict__ ws)
{
    __shared__ int cnt[N_STATIONS];
    __shared__ int cnt2[N_STATIONS];
    __shared__ int poff[N_STATIONS + 1];
    const int tid = threadIdx.x;
    for (int i = tid; i < N_STATIONS; i += 1024) { cnt[i] = 0; cnt2[i] = 0; }
    __syncthreads();
    for (int b = tid; b < BATCH; b += 1024) atomicAdd(&cnt[stations[b]], 1);
    __syncthreads();
    // wave-parallel inclusive scan of quad-ceil(cnt) over 5 chunks of 64
    if (tid < 64) {
        int run = 0;
        for (int base = 0; base < N_STATIONS; base += 64) {
            const int i = base + tid;
            int v = (i < N_STATIONS) ? ((cnt[i] + 3) & ~3) : 0;
#pragma unroll
            for (int off = 1; off < 64; off <<= 1) {
                int u = __shfl_up(v, off, 64);
                if (tid >= off) v += u;
            }
            if (i < N_STATIONS) poff[i + 1] = run + v;
            run += __shfl(v, 63, 64);
        }
        if (tid == 0) poff[0] = 0;
    }
    __syncthreads();
    int* order = ws + 1;
    for (int b = tid; b < BATCH; b += 1024) {
        int s = stations[b];
        int p = atomicAdd(&cnt2[s], 1);
        order[poff[s] + p] = b;          // within-station order irrelevant to output values
    }
    for (int s = tid; s < N_STATIONS; s += 1024) {
        int c = cnt[s], e = (c + 3) & ~3;
        for (int j = c; j < e; ++j) order[poff[s] + j] = -1;  // disjoint slots, no sync needed
    }
    if (tid == 0) ws[0] = poff[N_STATIONS] / 4;
}

__device__ __forceinline__ float dot4(float4 a, float4 b) {
    return a.x * b.x + a.y * b.y + a.z * b.z + a.w * b.w;
}

// ---------- kernel 2: one block per same-station sample QUAD ----------
// 256 thr = 8 groups x 32 lanes; group g computes rows g*12..g*12+11 for 4 samples.
// Reduction: sample-pairing butterfly (6 shuffles/row), batched 4 rows at a time
// so each xor-step's shuffles are independent (5 latency waits per batch, not 20).
__global__ __launch_bounds__(256, 4) void nlinear_quads(
    const float* __restrict__ z,        // (BATCH, CTX)
    const int*   __restrict__ stations,
    const float* __restrict__ W,        // (N_STATIONS, TGT, CTX)
    const float* __restrict__ bias,     // (N_STATIONS, TGT)
    const float* __restrict__ loc,
    const float* __restrict__ scale,
    const int*   __restrict__ ws,
    float*       __restrict__ out)      // (BATCH, TGT)
{
    // XCD swizzle: consecutive qids (same station) land on the same XCD's L2
    const int bid = blockIdx.x;
    const int qid = (bid & 7) * CPX + (bid >> 3);
    const int nquads = ws[0];
    if (qid >= nquads) return;

    const int* order = ws + 1;
    const int i0 = order[qid * 4];
    int i1 = order[qid * 4 + 1];
    int i2 = order[qid * 4 + 2];
    int i3 = order[qid * 4 + 3];
    const bool v1 = (i1 >= 0), v2 = (i2 >= 0), v3 = (i3 >= 0);
    if (!v1) i1 = i0;
    if (!v2) i2 = i0;
    if (!v3) i3 = i0;

    const int s = stations[i0];
    const float lc = loc[s], sc = scale[s], inv = 1.0f / sc;

    const int tid = threadIdx.x;
    const int t   = tid & 31;   // lane in 32-lane group
    const int grp = tid >> 5;   // group 0..7

    // normalized z -> registers: lane t owns float4s {t, t+32, t+64} of each sample
    const float4* z4 = reinterpret_cast<const float4*>(z);
    float4 z0[3], z1[3], z2[3], z3[3];
#pragma unroll
    for (int k = 0; k < 3; ++k) {
        float4 a = z4[(size_t)i0 * CTX4 + t + 32 * k];
        float4 b = z4[(size_t)i1 * CTX4 + t + 32 * k];
        float4 c = z4[(size_t)i2 * CTX4 + t + 32 * k];
        float4 d = z4[(size_t)i3 * CTX4 + t + 32 * k];
        z0[k].x = (a.x - lc) * inv; z0[k].y = (a.y - lc) * inv;
        z0[k].z = (a.z - lc) * inv; z0[k].w = (a.w - lc) * inv;
        z1[k].x = (b.x - lc) * inv; z1[k].y = (b.y - lc) * inv;
        z1[k].z = (b.z - lc) * inv; z1[k].w = (b.w - lc) * inv;
        z2[k].x = (c.x - lc) * inv; z2[k].y = (c.y - lc) * inv;
        z2[k].z = (c.z - lc) * inv; z2[k].w = (c.w - lc) * inv;
        z3[k].x = (d.x - lc) * inv; z3[k].y = (d.y - lc) * inv;
        z3[k].z = (d.z - lc) * inv; z3[k].w = (d.w - lc) * inv;
    }
    // launder: make z registers opaque so the compiler can't re-load/recompute them
#pragma unroll
    for (int k = 0; k < 3; ++k) {
        asm volatile("" : "+v"(z0[k].x), "+v"(z0[k].y), "+v"(z0[k].z), "+v"(z0[k].w));
        asm volatile("" : "+v"(z1[k].x), "+v"(z1[k].y), "+v"(z1[k].z), "+v"(z1[k].w));
        asm volatile("" : "+v"(z2[k].x), "+v"(z2[k].y), "+v"(z2[k].z), "+v"(z2[k].w));
        asm volatile("" : "+v"(z3[k].x), "+v"(z3[k].y), "+v"(z3[k].z), "+v"(z3[k].w));
    }

    const float4* w4 = reinterpret_cast<const float4*>(W) + (size_t)s * TGT * CTX4;
    const int row0 = grp * 12;

    for (int rb = 0; rb < 3; ++rb) {      // 3 sub-batches of 4 rows (VGPR containment)
        // --- phase 1: accumulate partials for 4 rows x 4 samples ---
        float a[4][4];
#pragma unroll
        for (int r = 0; r < 4; ++r) {
            const float4* wr = w4 + (size_t)(row0 + rb * 4 + r) * CTX4;
            const float4 w0 = wr[t];
            const float4 w1 = wr[t + 32];
            const float4 w2 = wr[t + 64];
            a[r][0] = dot4(w0, z0[0]) + dot4(w1, z0[1]) + dot4(w2, z0[2]);
            a[r][1] = dot4(w0, z1[0]) + dot4(w1, z1[1]) + dot4(w2, z1[2]);
            a[r][2] = dot4(w0, z2[0]) + dot4(w1, z2[1]) + dot4(w2, z2[2]);
            a[r][3] = dot4(w0, z3[0]) + dot4(w1, z3[1]) + dot4(w2, z3[2]);
        }
        // --- phase 2: batched pairing butterfly ---
        // step 1 (xor 1): fold samples {0,1} and {2,3}; 8 independent shuffles
        float u01[4], u23[4], v[4];
#pragma unroll
        for (int r = 0; r < 4; ++r) {
            u01[r] = ((t & 1) ? a[r][1] : a[r][0])
                   + __shfl_xor((t & 1) ? a[r][0] : a[r][1], 1, 64);
            u23[r] = ((t & 1) ? a[r][3] : a[r][2])
                   + __shfl_xor((t & 1) ? a[r][2] : a[r][3], 1, 64);
        }
        // step 2 (xor 2): fold {01} with {23}; 4 independent shuffles
#pragma unroll
        for (int r = 0; r < 4; ++r)
            v[r] = ((t & 2) ? u23[r] : u01[r])
                 + __shfl_xor((t & 2) ? u01[r] : u23[r], 2, 64);
        // steps 3-5: plain butterflies, 4 independent shuffles each
#pragma unroll
        for (int r = 0; r < 4; ++r) v[r] += __shfl_xor(v[r], 4, 64);
#pragma unroll
        for (int r = 0; r < 4; ++r) v[r] += __shfl_xor(v[r], 8, 64);
#pragma unroll
        for (int r = 0; r < 4; ++r) v[r] += __shfl_xor(v[r], 16, 64);
        // v[r] on lane with (t&3)==j = full 32-lane sum for sample j, row rb*4+r

        // --- epilogue: lanes 0..3 write their sample's 4 rows ---
        const bool wv = (t == 0) || (t == 1 && v1) || (t == 2 && v2) || (t == 3 && v3);
        if (wv) {
            const int id = (t == 0) ? i0 : (t == 1) ? i1 : (t == 2) ? i2 : i3;
#pragma unroll
            for (int r = 0; r < 4; ++r) {
                const int row = row0 + rb * 4 + r;
                float val = (v[r] + bias[(size_t)s * TGT + row]) * sc + lc;
                out[(size_t)id * TGT + row] = fmaxf(val, 0.f) + log1pf(expf(-fabsf(val)));
            }
        }
    }
}

extern "C" void kernel_launch(void* const* d_in, const int* in_sizes, int n_in,
                              void* d_out, int out_size, void* d_ws, size_t ws_size,
                              hipStream_t stream) {
    const float* z        = (const float*)d_in[0];
    const int*   stations = (const int*)  d_in[1];
    const float* W        = (const float*)d_in[2];
    const float* bias     = (const float*)d_in[3];
    const float* loc      = (const float*)d_in[4];
    const float* scale    = (const float*)d_in[5];
    float* out = (float*)d_out;
    int* ws = (int*)d_ws;

    build_quads<<<1, 1024, 0, stream>>>(stations, ws);
    nlinear_quads<<<NWG, 256, 0, stream>>>(z, stations, W, bias, loc, scale, ws, out);
}